// Round 5
// baseline (107.512 us; speedup 1.0000x reference)
//
#include <hip/hip_runtime.h>
#include <math.h>

#define NR 8
#define NB 8
#define NH 32
#define NKVH 8
#define NG 4
#define ND 128
#define NDV 128
#define NPAGE 2048
#define KSTR (NKVH*ND)        // 1024 floats per page (all kvh slices)
#define NCH 8                 // page-chunks per rank
#define CHUNK 256             // pages per chunk
#define NPART (NR*NCH)        // 64 partial slots
#define PSTRIDE (NB*NKVH*NG)  // 256 output rows
#define QSCALE 0.088388347648318447f
#define DEFER_THR 8.0f

// ---------------- histogram: cnt[r][b][pg] = multiplicity in first len entries
__global__ __launch_bounds__(256) void build_counts(
    const int* __restrict__ kv_lens, const int* __restrict__ bt_all,
    int* __restrict__ cnt) {
  const int rb = blockIdx.x;             // r*NB + b
  __shared__ int h[NPAGE];
  for (int i = threadIdx.x; i < NPAGE; i += 256) h[i] = 0;
  __syncthreads();
  const int len = kv_lens[rb];
  const int* bt = bt_all + (size_t)rb * NPAGE;
  for (int i = threadIdx.x; i < len; i += 256) atomicAdd(&h[bt[i]], 1);
  __syncthreads();
  int* o = cnt + (size_t)rb * NPAGE;
  for (int i = threadIdx.x; i < NPAGE; i += 256) o[i] = h[i];
}

// ---------------- weighted-stream attention partials
// block = (r, kvh, chunk of 256 pages); 4 waves: ph = page-half, gp = g-pair.
// lane: myb = lane&7 (batch), dg = (lane>>3)&7 (dims 16*dg .. +15).
__global__ __launch_bounds__(256, 2) void attn_partial(
    const float* __restrict__ q,
    const float* __restrict__ k_cache,
    const float* __restrict__ v_cache,
    const int* __restrict__ cnt,
    float* __restrict__ ws_out,   // [NPART][NB][NKVH][NG][NDV]
    float* __restrict__ ws_lse)   // [NPART][NB][NKVH][NG]
{
  const int bid   = blockIdx.x;
  const int r     = bid & 7;              // XCD swizzle: rank pinned per XCD
  const int kvh   = (bid >> 3) & 7;
  const int chunk = bid >> 6;             // 0..7

  const int tid  = threadIdx.x;
  const int wid  = tid >> 6;
  const int ph   = wid >> 1;              // page half: 128 pages
  const int gp   = wid & 1;               // g-pair: heads {2gp, 2gp+1}
  const int lane = tid & 63;
  const int myb  = lane & 7;
  const int dg   = (lane >> 3) & 7;

  __shared__ float cl[CHUNK][9];          // counts, padded row
  __shared__ float Sm[2][2][8][2][2];     // [ph][gp][b][g'] {m,l}
  __shared__ float Sacc[2][2][8][2][NDV]; // 32 KB

  // stage counts -> LDS as float (coalesced: one b per 256-thread pass)
  for (int i = tid; i < CHUNK * 8; i += 256) {
    const int b   = i >> 8;
    const int pgl = i & 255;
    cl[pgl][b] = (float)cnt[((size_t)(r * NB + b)) * NPAGE + chunk * CHUNK + pgl];
  }

  // q fragments: my b, 2 heads, dims 16*dg..+15 (pre-scaled)
  float4 qv[2][4];
  {
    const float* qp = q + ((size_t)myb * NH + kvh * NG + gp * 2) * ND + 16 * dg;
#pragma unroll
    for (int g = 0; g < 2; ++g)
#pragma unroll
      for (int x = 0; x < 4; ++x) {
        float4 t = *(const float4*)(qp + g * ND + 4 * x);
        t.x *= QSCALE; t.y *= QSCALE; t.z *= QSCALE; t.w *= QSCALE;
        qv[g][x] = t;
      }
  }
  __syncthreads();

  float m0 = -INFINITY, m1 = -INFINITY, l0 = 0.f, l1 = 0.f;
  float4 A0[4], A1[4];
#pragma unroll
  for (int x = 0; x < 4; ++x) {
    A0[x] = make_float4(0.f, 0.f, 0.f, 0.f);
    A1[x] = make_float4(0.f, 0.f, 0.f, 0.f);
  }

  const int pg0 = chunk * CHUNK + ph * 128;
  const float* Kp = k_cache + ((size_t)r * NPAGE + pg0) * KSTR + kvh * ND  + 16 * dg;
  const float* Vp = v_cache + ((size_t)r * NPAGE + pg0) * KSTR + kvh * NDV + 16 * dg;

#pragma unroll 4
  for (int j = 0; j < 128; ++j) {
    const float* kp = Kp + (size_t)j * KSTR;
    const float* vp = Vp + (size_t)j * KSTR;
    float4 k[4], v[4];
#pragma unroll
    for (int x = 0; x < 4; ++x) {
      k[x] = *(const float4*)(kp + 4 * x);
      v[x] = *(const float4*)(vp + 4 * x);
    }
    const float c = cl[ph * 128 + j][myb];

    float s0 = 0.f, s1 = 0.f;
#pragma unroll
    for (int x = 0; x < 4; ++x) {
      s0 += k[x].x * qv[0][x].x + k[x].y * qv[0][x].y
          + k[x].z * qv[0][x].z + k[x].w * qv[0][x].w;
      s1 += k[x].x * qv[1][x].x + k[x].y * qv[1][x].y
          + k[x].z * qv[1][x].z + k[x].w * qv[1][x].w;
    }
#pragma unroll
    for (int mk = 8; mk <= 32; mk <<= 1) {
      s0 += __shfl_xor(s0, mk);
      s1 += __shfl_xor(s1, mk);
    }

    // defer-max online softmax (weights c; c=0 pages contribute nothing)
    const bool need = (s0 - m0 > DEFER_THR) || (s1 - m1 > DEFER_THR);
    if (__any(need)) {                    // rare path: true rescale
      {
        const float mn = fmaxf(m0, s0);
        const float sc = __expf(m0 - mn);
        const float e  = c * __expf(s0 - mn);
        m0 = mn; l0 = l0 * sc + e;
#pragma unroll
        for (int x = 0; x < 4; ++x) {
          A0[x].x = A0[x].x * sc + e * v[x].x;
          A0[x].y = A0[x].y * sc + e * v[x].y;
          A0[x].z = A0[x].z * sc + e * v[x].z;
          A0[x].w = A0[x].w * sc + e * v[x].w;
        }
      }
      {
        const float mn = fmaxf(m1, s1);
        const float sc = __expf(m1 - mn);
        const float e  = c * __expf(s1 - mn);
        m1 = mn; l1 = l1 * sc + e;
#pragma unroll
        for (int x = 0; x < 4; ++x) {
          A1[x].x = A1[x].x * sc + e * v[x].x;
          A1[x].y = A1[x].y * sc + e * v[x].y;
          A1[x].z = A1[x].z * sc + e * v[x].z;
          A1[x].w = A1[x].w * sc + e * v[x].w;
        }
      }
    } else {                              // fast path: no rescale
      const float e0 = c * __expf(s0 - m0);
      const float e1 = c * __expf(s1 - m1);
      l0 += e0; l1 += e1;
#pragma unroll
      for (int x = 0; x < 4; ++x) {
        A0[x].x += e0 * v[x].x; A0[x].y += e0 * v[x].y;
        A0[x].z += e0 * v[x].z; A0[x].w += e0 * v[x].w;
        A1[x].x += e1 * v[x].x; A1[x].y += e1 * v[x].y;
        A1[x].z += e1 * v[x].z; A1[x].w += e1 * v[x].w;
      }
    }
  }

  // ---- stash per-wave state
  if (dg == 0) {
    Sm[ph][gp][myb][0][0] = m0; Sm[ph][gp][myb][0][1] = l0;
    Sm[ph][gp][myb][1][0] = m1; Sm[ph][gp][myb][1][1] = l1;
  }
#pragma unroll
  for (int x = 0; x < 4; ++x) {
    *(float4*)&Sacc[ph][gp][myb][0][16 * dg + 4 * x] = A0[x];
    *(float4*)&Sacc[ph][gp][myb][1][16 * dg + 4 * x] = A1[x];
  }
  __syncthreads();

  // ---- merge the two page-halves, normalize, write partial
  // thread -> (row = gp,b,g') x (16 dims)
  const int row = tid >> 3;       // 0..31
  const int db  = tid & 7;        // dim block of 16
  const int ogp = row >> 4;
  const int ob  = (row >> 1) & 7;
  const int og  = row & 1;

  const float ma = Sm[0][ogp][ob][og][0], la = Sm[0][ogp][ob][og][1];
  const float mb = Sm[1][ogp][ob][og][0], lb = Sm[1][ogp][ob][og][1];
  const float M  = fmaxf(ma, mb);
  const float wa = (ma > -1e37f) ? __expf(ma - M) : 0.f;
  const float wb = (mb > -1e37f) ? __expf(mb - M) : 0.f;
  const float L  = la * wa + lb * wb;
  const float inv = (L > 0.f) ? 1.f / L : 0.f;

  const int pi = r * NCH + chunk;
  const size_t prow = (((size_t)pi * NB + ob) * NKVH + kvh) * NG + (ogp * 2 + og);
  float* orow = ws_out + prow * NDV + 16 * db;
#pragma unroll
  for (int x = 0; x < 4; ++x) {
    const int d = 16 * db + 4 * x;
    float4 o;
    o.x = (Sacc[0][ogp][ob][og][d]     * wa + Sacc[1][ogp][ob][og][d]     * wb) * inv;
    o.y = (Sacc[0][ogp][ob][og][d + 1] * wa + Sacc[1][ogp][ob][og][d + 1] * wb) * inv;
    o.z = (Sacc[0][ogp][ob][og][d + 2] * wa + Sacc[1][ogp][ob][og][d + 2] * wb) * inv;
    o.w = (Sacc[0][ogp][ob][og][d + 3] * wa + Sacc[1][ogp][ob][og][d + 3] * wb) * inv;
    *(float4*)(orow + 4 * x) = o;
  }
  if (db == 0) ws_lse[prow] = (L > 0.f) ? (M + __logf(L)) : -1e30f;
}

// ---------------- combine over NPART partials per (b,kvh,g)
__global__ __launch_bounds__(128) void attn_combine(
    const float* __restrict__ ws_out,
    const float* __restrict__ ws_lse,
    float* __restrict__ out)
{
  const int bkg = blockIdx.x;
  const int d   = threadIdx.x;

  float mg = -INFINITY;
#pragma unroll 16
  for (int p = 0; p < NPART; ++p)
    mg = fmaxf(mg, ws_lse[p * PSTRIDE + bkg]);

  float denom = 0.f, acc = 0.f;
#pragma unroll 8
  for (int p = 0; p < NPART; ++p) {
    const float e = __expf(ws_lse[p * PSTRIDE + bkg] - mg);
    denom += e;
    acc += e * ws_out[((size_t)p * PSTRIDE + bkg) * NDV + d];
  }
  out[(size_t)bkg * NDV + d] = acc / denom;
}

extern "C" void kernel_launch(void* const* d_in, const int* in_sizes, int n_in,
                              void* d_out, int out_size, void* d_ws, size_t ws_size,
                              hipStream_t stream) {
  const float* q        = (const float*)d_in[0];
  const float* k_cache  = (const float*)d_in[1];
  const float* v_cache  = (const float*)d_in[2];
  const int*   kv_lens  = (const int*)d_in[3];
  const int*   bt       = (const int*)d_in[4];
  float* out = (float*)d_out;

  float* ws_out = (float*)d_ws;                                   // 8.39 MB
  float* ws_lse = ws_out + (size_t)NPART * PSTRIDE * NDV;         // 64 KB
  int*   cnt    = (int*)(ws_lse + NPART * PSTRIDE);               // 512 KB

  build_counts<<<NR * NB, 256, 0, stream>>>(kv_lens, bt, cnt);
  attn_partial<<<NR * NKVH * NCH, 256, 0, stream>>>(
      q, k_cache, v_cache, cnt, ws_out, ws_lse);
  attn_combine<<<NB * NKVH * NG, NDV, 0, stream>>>(ws_out, ws_lse, out);
}